// Round 3
// baseline (4211.131 us; speedup 1.0000x reference)
//
#include <hip/hip_runtime.h>
#include <hip/hip_bf16.h>
#include <math.h>

#define N_NODES 50000
#define N_EDGES 800000

typedef __hip_bfloat16 bf16;

__device__ __forceinline__ float b2f(bf16 v){ return __bfloat162float(v); }
__device__ __forceinline__ bf16 f2b(float v){ return __float2bfloat16(v); }

template<typename T> __device__ __forceinline__ float ldf(const T* p, size_t i);
template<> __device__ __forceinline__ float ldf<float>(const float* p, size_t i){ return p[i]; }
template<> __device__ __forceinline__ float ldf<bf16>(const bf16* p, size_t i){ return b2f(p[i]); }

template<typename T> __device__ __forceinline__ void stf(T* p, size_t i, float v);
template<> __device__ __forceinline__ void stf<float>(float* p, size_t i, float v){ p[i] = v; }
template<> __device__ __forceinline__ void stf<bf16>(bf16* p, size_t i, float v){ p[i] = f2b(v); }

// flags[0] = edge_index is int64; flags[1] = float tensors are float32
__global__ void detect_kernel(const int* __restrict__ ei,
                              const unsigned int* __restrict__ xw,
                              int* __restrict__ flags){
    if (threadIdx.x == 0 && blockIdx.x == 0){
        int i64 = 1;
        for (int j = 0; j < 256; ++j)
            if (ei[2*j + 1] != 0){ i64 = 0; break; }
        flags[0] = i64;
        // float32 data => low half-words are mantissa garbage => some decode huge
        int isf32 = 0;
        for (int j = 0; j < 64; ++j){
            unsigned int w = xw[j];
            float lo = __uint_as_float((w & 0xFFFFu) << 16);
            if (!(fabsf(lo) <= 64.f)){ isf32 = 1; break; }   // catches inf/NaN too
        }
        flags[1] = isf32;
    }
}

// ---------------- projections: q,k,v = x @ W + b  (one node per block) -------
// XT = dtype of x, WT = dtype of weights; outputs stored bf16.
template<typename XT, typename WT, int K>
__global__ __launch_bounds__(256) void proj_kernel(
    const XT* __restrict__ x,
    const WT* __restrict__ qw, const WT* __restrict__ qb,
    const WT* __restrict__ kw, const WT* __restrict__ kb,
    const WT* __restrict__ vw, const WT* __restrict__ vb,
    bf16* __restrict__ q, bf16* __restrict__ k, bf16* __restrict__ v,
    const int* __restrict__ flags)
{
    if (flags[1] != (sizeof(WT) == 4 ? 1 : 0)) return;
    __shared__ float xs[K];
    const int i = blockIdx.x;
    const int t = threadIdx.x;
    if (t < K) xs[t] = ldf(x, (size_t)i*K + t);
    __syncthreads();
    float aq = ldf(qb, t);
    float ak = ldf(kb, t);
    float av = ldf(vb, t);
    #pragma unroll 8
    for (int kk = 0; kk < K; ++kk){
        const float xv = xs[kk];
        aq += xv * ldf(qw, kk*256 + t);
        ak += xv * ldf(kw, kk*256 + t);
        av += xv * ldf(vw, kk*256 + t);
    }
    const size_t o = (size_t)i*256 + t;
    q[o] = f2b(aq); k[o] = f2b(ak); v[o] = f2b(av);
}

// ---- fused edge pass: a = exp(q.(k+e)/sqrt(C)); s += a; msg += a*(v+e) -----
// (no segment-max: exp(a)/sum exp(a) == exp(a-m)/sum exp(a-m) exactly)
template<typename WT, int HEADS>
__global__ __launch_bounds__(256) void edge_pass(
    const bf16* __restrict__ q, const bf16* __restrict__ k,
    const bf16* __restrict__ v,
    const int* __restrict__ ei, const WT* __restrict__ ea,
    const WT* __restrict__ ew, const int* __restrict__ flags,
    float* __restrict__ s, float* __restrict__ msgacc)
{
    if (flags[1] != (sizeof(WT) == 4 ? 1 : 0)) return;
    const int e = blockIdx.x*4 + (threadIdx.x >> 6);
    if (e >= N_EDGES) return;
    const int lane = threadIdx.x & 63;
    const bool i64 = (flags[0] != 0);
    const int src = i64 ? ei[2*e]             : ei[e];
    const int dst = i64 ? ei[2*(N_EDGES + e)] : ei[N_EDGES + e];
    if ((unsigned)src >= N_NODES || (unsigned)dst >= N_NODES) return;
    const float eav = ldf(ea, e);

    if (HEADS == 4){
        #pragma unroll
        for (int h = 0; h < 4; ++h){
            const int c = h*64 + lane;
            const float ev = eav * ldf(ew, c);
            float p = b2f(q[(size_t)dst*256 + c]) *
                      (b2f(k[(size_t)src*256 + c]) + ev);
            #pragma unroll
            for (int off = 1; off < 64; off <<= 1) p += __shfl_xor(p, off, 64);
            const float a = expf(fminf(p * 0.125f, 80.f));   // 1/sqrt(64)
            if (lane == 0) atomicAdd(&s[dst*4 + h], a);
            const float val = a * (b2f(v[(size_t)src*256 + c]) + ev);
            atomicAdd(&msgacc[(size_t)dst*256 + c], val);
        }
    } else {
        float ev[4], vv[4];
        float p = 0.f;
        #pragma unroll
        for (int j = 0; j < 4; ++j){
            const int c = j*64 + lane;
            ev[j] = eav * ldf(ew, c);
            vv[j] = b2f(v[(size_t)src*256 + c]) + ev[j];
            p += b2f(q[(size_t)dst*256 + c]) *
                 (b2f(k[(size_t)src*256 + c]) + ev[j]);
        }
        #pragma unroll
        for (int off = 1; off < 64; off <<= 1) p += __shfl_xor(p, off, 64);
        const float a = expf(fminf(p * 0.0625f, 80.f));      // 1/sqrt(256)
        if (lane == 0) atomicAdd(&s[dst], a);
        #pragma unroll
        for (int j = 0; j < 4; ++j)
            atomicAdd(&msgacc[(size_t)dst*256 + j*64 + lane], a * vv[j]);
    }
}

// ------- node epilogue: out = msg/(s+eps) + x@skw+skb; LN (+ReLU) -----------
template<typename XT, typename WT, typename OT, int K, int HEADS, bool RELU>
__global__ __launch_bounds__(256) void node_epilogue(
    const float* __restrict__ msgacc, const float* __restrict__ s,
    const XT* __restrict__ xin,
    const WT* __restrict__ skw, const WT* __restrict__ skb,
    const WT* __restrict__ g, const WT* __restrict__ bb,
    OT* __restrict__ out, const int* __restrict__ flags)
{
    if (flags[1] != (sizeof(WT) == 4 ? 1 : 0)) return;
    __shared__ float xs[K];
    __shared__ float red1[4];
    __shared__ float red2[4];
    const int i = blockIdx.x;
    const int t = threadIdx.x;
    if (t < K) xs[t] = ldf(xin, (size_t)i*K + t);
    __syncthreads();
    float acc = ldf(skb, t);
    #pragma unroll 8
    for (int kk = 0; kk < K; ++kk)
        acc += xs[kk] * ldf(skw, kk*256 + t);
    const int h = (HEADS == 4) ? (t >> 6) : 0;
    const float denom = s[i*HEADS + h] + 1e-16f;
    const float val = msgacc[(size_t)i*256 + t] / denom + acc;

    // LayerNorm over 256 (4 waves)
    const int wid = t >> 6, lane = t & 63;
    float sum = val;
    #pragma unroll
    for (int off = 1; off < 64; off <<= 1) sum += __shfl_xor(sum, off, 64);
    if (lane == 0) red1[wid] = sum;
    __syncthreads();
    const float mu = (red1[0] + red1[1] + red1[2] + red1[3]) * (1.f/256.f);
    const float d = val - mu;
    float vs = d * d;
    #pragma unroll
    for (int off = 1; off < 64; off <<= 1) vs += __shfl_xor(vs, off, 64);
    if (lane == 0) red2[wid] = vs;
    __syncthreads();
    const float var = (red2[0] + red2[1] + red2[2] + red2[3]) * (1.f/256.f);
    float y = d * rsqrtf(var + 1e-5f) * b2f(f2b(0.f) /*dummy*/) ;
    y = d * rsqrtf(var + 1e-5f) * ldf(g, t) + ldf(bb, t);
    if (RELU) y = fmaxf(y, 0.f);
    stf(out, (size_t)i*256 + t, y);
}

template<typename T>
static void launch_pipeline(void* const* d_in, void* d_out, char* w, hipStream_t stream,
                            const int* flags)
{
    const T* x  = (const T*)d_in[0];
    const int* ei = (const int*)d_in[1];
    const T* ea = (const T*)d_in[2];
    const T* qw0 = (const T*)d_in[3],  *qb0 = (const T*)d_in[4];
    const T* kw0 = (const T*)d_in[5],  *kb0 = (const T*)d_in[6];
    const T* vw0 = (const T*)d_in[7],  *vb0 = (const T*)d_in[8];
    const T* ew0 = (const T*)d_in[9];
    const T* sw0 = (const T*)d_in[10], *sb0 = (const T*)d_in[11];
    const T* g0  = (const T*)d_in[12], *b0  = (const T*)d_in[13];
    const T* qw1 = (const T*)d_in[14], *qb1 = (const T*)d_in[15];
    const T* kw1 = (const T*)d_in[16], *kb1 = (const T*)d_in[17];
    const T* vw1 = (const T*)d_in[18], *vb1 = (const T*)d_in[19];
    const T* ew1 = (const T*)d_in[20];
    const T* sw1 = (const T*)d_in[21], *sb1 = (const T*)d_in[22];
    const T* g1  = (const T*)d_in[23], *b1  = (const T*)d_in[24];

    bf16*  q      = (bf16*)(w + 0);
    bf16*  k      = (bf16*)(w + 25600000);
    bf16*  v      = (bf16*)(w + 51200000);
    bf16*  hbuf   = (bf16*)(w + 76800000);
    float* msgacc = (float*)(w + 102400000);
    float* s      = (float*)(w + 153600000);

    const int EB = (N_EDGES + 3) / 4;

    // layer 0
    proj_kernel<T, T, 128><<<N_NODES, 256, 0, stream>>>(
        x, qw0,qb0, kw0,kb0, vw0,vb0, q,k,v, flags);
    edge_pass<T, 4><<<EB, 256, 0, stream>>>(q, k, v, ei, ea, ew0, flags, s, msgacc);
    node_epilogue<T, T, bf16, 128, 4, true><<<N_NODES, 256, 0, stream>>>(
        msgacc, s, x, sw0, sb0, g0, b0, hbuf, flags);
}

template<typename T>
static void launch_pipeline2(void* const* d_in, void* d_out, char* w, hipStream_t stream,
                             const int* flags)
{
    const int* ei = (const int*)d_in[1];
    const T* ea = (const T*)d_in[2];
    const T* qw1 = (const T*)d_in[14], *qb1 = (const T*)d_in[15];
    const T* kw1 = (const T*)d_in[16], *kb1 = (const T*)d_in[17];
    const T* vw1 = (const T*)d_in[18], *vb1 = (const T*)d_in[19];
    const T* ew1 = (const T*)d_in[20];
    const T* sw1 = (const T*)d_in[21], *sb1 = (const T*)d_in[22];
    const T* g1  = (const T*)d_in[23], *b1  = (const T*)d_in[24];

    bf16*  q      = (bf16*)(w + 0);
    bf16*  k      = (bf16*)(w + 25600000);
    bf16*  v      = (bf16*)(w + 51200000);
    bf16*  hbuf   = (bf16*)(w + 76800000);
    float* msgacc = (float*)(w + 102400000);
    float* s      = (float*)(w + 153600000);

    const int EB = (N_EDGES + 3) / 4;

    proj_kernel<bf16, T, 256><<<N_NODES, 256, 0, stream>>>(
        hbuf, qw1,qb1, kw1,kb1, vw1,vb1, q,k,v, flags);
    edge_pass<T, 1><<<EB, 256, 0, stream>>>(q, k, v, ei, ea, ew1, flags, s, msgacc);
    node_epilogue<bf16, T, T, 256, 1, false><<<N_NODES, 256, 0, stream>>>(
        msgacc, s, hbuf, sw1, sb1, g1, b1, (T*)d_out, flags);
}

extern "C" void kernel_launch(void* const* d_in, const int* in_sizes, int n_in,
                              void* d_out, int out_size, void* d_ws, size_t ws_size,
                              hipStream_t stream) {
    char* w = (char*)d_ws;
    float* msgacc = (float*)(w + 102400000);
    float* s      = (float*)(w + 153600000);
    int*   flags  = (int*)  (w + 154400000);

    detect_kernel<<<1, 64, 0, stream>>>(
        (const int*)d_in[1], (const unsigned int*)d_in[0], flags);

    // ---------------- layer 0 ----------------
    hipMemsetAsync(msgacc, 0, (size_t)N_NODES*256*4, stream);
    hipMemsetAsync(s,      0, (size_t)N_NODES*4*4, stream);
    launch_pipeline<bf16>(d_in, d_out, w, stream, flags);
    launch_pipeline<float>(d_in, d_out, w, stream, flags);

    // ---------------- layer 1 ----------------
    hipMemsetAsync(msgacc, 0, (size_t)N_NODES*256*4, stream);
    hipMemsetAsync(s,      0, (size_t)N_NODES*4, stream);
    launch_pipeline2<bf16>(d_in, d_out, w, stream, flags);
    launch_pipeline2<float>(d_in, d_out, w, stream, flags);
}

// Round 4
// 1904.539 us; speedup vs baseline: 2.2111x; 2.2111x over previous
//
#include <hip/hip_runtime.h>
#include <hip/hip_bf16.h>
#include <math.h>

#define N_NODES 50000
#define N_EDGES 800000

typedef __hip_bfloat16 bf16;
typedef __attribute__((ext_vector_type(8))) short frag_ab;   // 8 bf16
typedef __attribute__((ext_vector_type(4))) float frag_cd;   // 4 f32

__device__ __forceinline__ float b2f(bf16 v){ return __bfloat162float(v); }
__device__ __forceinline__ bf16 f2b(float v){ return __float2bfloat16(v); }
// runtime-dtype load (flag: 1 = float32 tensors, 0 = bf16)
__device__ __forceinline__ float ldrt(const void* p, size_t i, bool f32){
    return f32 ? ((const float*)p)[i] : b2f(((const bf16*)p)[i]);
}

// flags[0] = edge_index is int64; flags[1] = float tensors are float32
__global__ void detect_kernel(const int* __restrict__ ei,
                              const unsigned int* __restrict__ xw,
                              int* __restrict__ flags){
    if (threadIdx.x == 0 && blockIdx.x == 0){
        int i64 = 1;
        for (int j = 0; j < 256; ++j)
            if (ei[2*j + 1] != 0){ i64 = 0; break; }
        flags[0] = i64;
        int isf32 = 0;
        for (int j = 0; j < 64; ++j){
            unsigned int w = xw[j];
            float lo = __uint_as_float((w & 0xFFFFu) << 16);
            if (!(fabsf(lo) <= 64.f)){ isf32 = 1; break; }
        }
        flags[1] = isf32;
    }
}

// ---- convert x -> bf16 xb [N,128] ------------------------------------------
__global__ __launch_bounds__(256) void conv_x(const void* __restrict__ xin,
                                              bf16* __restrict__ xb,
                                              const int* __restrict__ flags){
    const size_t i = ((size_t)blockIdx.x*256 + threadIdx.x) * 8;
    if (i >= (size_t)N_NODES*128) return;
    if (flags[1]){
        const float* xf = (const float*)xin;
        #pragma unroll
        for (int j = 0; j < 8; ++j) xb[i+j] = f2b(xf[i+j]);
    } else {
        *(uint4*)(xb + i) = *(const uint4*)((const bf16*)xin + i);
    }
}

// ---- convert 6 small vectors (256 each) -> f32 -----------------------------
__global__ void conv_vec6(const void* p0, const void* p1, const void* p2,
                          const void* p3, const void* p4, const void* p5,
                          float* __restrict__ outv, const int* __restrict__ flags){
    const int t = threadIdx.x;
    const bool f32 = flags[1] != 0;
    outv[0*256+t] = ldrt(p0, t, f32);
    outv[1*256+t] = ldrt(p1, t, f32);
    outv[2*256+t] = ldrt(p2, t, f32);
    outv[3*256+t] = ldrt(p3, t, f32);
    outv[4*256+t] = ldrt(p4, t, f32);
    outv[5*256+t] = ldrt(p5, t, f32);
}

// ---- transpose 4 weight mats [K,256] -> Wt[1024][K] bf16, biases -> f32 ----
template<int K>
__global__ __launch_bounds__(256) void trans_w(
    const void* w0, const void* w1, const void* w2, const void* w3,
    const void* b0, const void* b1, const void* b2, const void* b3,
    bf16* __restrict__ Wt, float* __restrict__ biasf,
    const int* __restrict__ flags)
{
    const bool f32 = flags[1] != 0;
    const int mi = blockIdx.y;
    const void* W = mi==0?w0 : mi==1?w1 : mi==2?w2 : w3;
    const void* B = mi==0?b0 : mi==1?b1 : mi==2?b2 : b3;
    const int t = threadIdx.x;                  // k index (lanes -> coalesced Wt writes)
    if (blockIdx.x == 0) biasf[mi*256 + t] = ldrt(B, t, f32);
    if (t >= K) return;
    const int c0 = blockIdx.x * 16;
    for (int c = c0; c < c0 + 16; ++c)
        Wt[(size_t)(mi*256 + c)*K + t] = f2b(ldrt(W, (size_t)t*256 + c, f32));
}

// ---- MFMA GEMM: P[:, 0:768] = X@W(qkv)+b (stride 768), cols 768.. -> skipb --
#define AST 40   // LDS row stride in shorts (64B data + 16B pad -> 2-way only)
template<int K>
__global__ __launch_bounds__(256) void gemm_qkvs(
    const bf16* __restrict__ X,     // [N_NODES, K]
    const bf16* __restrict__ Wt,    // [1024, K]
    const float* __restrict__ bias, // [1024]
    bf16* __restrict__ P,           // [N_NODES, 768]
    bf16* __restrict__ skipb)       // [N_NODES, 256]
{
    __shared__ short As[64*AST];
    __shared__ short Bs[64*AST];
    const int t = threadIdx.x;
    const int wid = t >> 6, lane = t & 63;
    const int quad = lane >> 4, l16 = lane & 15;
    const int m0 = blockIdx.x * 64;
    const int n0 = blockIdx.y * 64;
    const int srow = t >> 2;          // 0..63
    const int scg  = (t & 3) * 8;     // 0,8,16,24 (bf16 elems)
    const int arow = m0 + srow;

    frag_cd acc[4] = {};
    for (int k0 = 0; k0 < K; k0 += 32){
        uint4 av = {0,0,0,0};
        if (arow < N_NODES)
            av = *(const uint4*)(X + (size_t)arow*K + k0 + scg);
        *(uint4*)(&As[srow*AST + scg]) = av;
        uint4 bv = *(const uint4*)(Wt + (size_t)(n0 + srow)*K + k0 + scg);
        *(uint4*)(&Bs[srow*AST + scg]) = bv;
        __syncthreads();
        frag_ab af = *(const frag_ab*)(&As[(wid*16 + l16)*AST + quad*8]);
        #pragma unroll
        for (int nt = 0; nt < 4; ++nt){
            frag_ab bf = *(const frag_ab*)(&Bs[(nt*16 + l16)*AST + quad*8]);
            acc[nt] = __builtin_amdgcn_mfma_f32_16x16x32_bf16(af, bf, acc[nt], 0, 0, 0);
        }
        __syncthreads();
    }
    #pragma unroll
    for (int nt = 0; nt < 4; ++nt){
        const int gc = n0 + nt*16 + l16;          // global col 0..1023
        const float bsum = bias[gc];
        #pragma unroll
        for (int r = 0; r < 4; ++r){
            const int node = m0 + wid*16 + quad*4 + r;   // C/D: row=quad*4+reg
            if (node < N_NODES){
                const float y = acc[nt][r] + bsum;
                if (gc < 768) P[(size_t)node*768 + gc] = f2b(y);
                else          skipb[(size_t)node*256 + (gc - 768)] = f2b(y);
            }
        }
    }
}

// ---- fused edge pass: a = exp(q.(k+e)/sqrt(C)); s += a; msg += a*(v+e) -----
template<int HEADS>
__global__ __launch_bounds__(256) void edge_pass(
    const bf16* __restrict__ P,     // qkv, stride 768
    const int* __restrict__ ei, const void* __restrict__ ea,
    const float* __restrict__ ewf, const int* __restrict__ flags,
    float* __restrict__ s, float* __restrict__ msgacc)
{
    const int e = blockIdx.x*4 + (threadIdx.x >> 6);
    if (e >= N_EDGES) return;
    const int lane = threadIdx.x & 63;
    const bool i64 = flags[0] != 0;
    const bool f32 = flags[1] != 0;
    const int src = i64 ? ei[2*e]             : ei[e];
    const int dst = i64 ? ei[2*(N_EDGES + e)] : ei[N_EDGES + e];
    if ((unsigned)src >= N_NODES || (unsigned)dst >= N_NODES) return;
    const float eav = f32 ? ((const float*)ea)[e] : b2f(((const bf16*)ea)[e]);
    const bf16* qrow = P + (size_t)dst*768;
    const bf16* krow = P + (size_t)src*768 + 256;
    const bf16* vrow = P + (size_t)src*768 + 512;

    if (HEADS == 4){
        #pragma unroll
        for (int h = 0; h < 4; ++h){
            const int c = h*64 + lane;
            const float ev = eav * ewf[c];
            float p = b2f(qrow[c]) * (b2f(krow[c]) + ev);
            #pragma unroll
            for (int off = 1; off < 64; off <<= 1) p += __shfl_xor(p, off, 64);
            const float a = expf(fminf(p * 0.125f, 80.f));   // 1/sqrt(64)
            if (lane == 0) atomicAdd(&s[dst*4 + h], a);
            atomicAdd(&msgacc[(size_t)dst*256 + c], a * (b2f(vrow[c]) + ev));
        }
    } else {
        float ev[4], vv[4];
        float p = 0.f;
        #pragma unroll
        for (int j = 0; j < 4; ++j){
            const int c = j*64 + lane;
            ev[j] = eav * ewf[c];
            vv[j] = b2f(vrow[c]) + ev[j];
            p += b2f(qrow[c]) * (b2f(krow[c]) + ev[j]);
        }
        #pragma unroll
        for (int off = 1; off < 64; off <<= 1) p += __shfl_xor(p, off, 64);
        const float a = expf(fminf(p * 0.0625f, 80.f));      // 1/sqrt(256)
        if (lane == 0) atomicAdd(&s[dst], a);
        #pragma unroll
        for (int j = 0; j < 4; ++j)
            atomicAdd(&msgacc[(size_t)dst*256 + j*64 + lane], a * vv[j]);
    }
}

// ---- node epilogue: val = msg/(s+eps) + skip; LN (+ReLU); store ------------
// outmode 0: always bf16; 1: dtype per flags[1]
template<int HEADS, bool RELU>
__global__ __launch_bounds__(256) void node_epilogue(
    const float* __restrict__ msgacc, const float* __restrict__ s,
    const bf16* __restrict__ skip,
    const float* __restrict__ gf, const float* __restrict__ bf_,
    void* __restrict__ out, const int* __restrict__ flags, int outmode)
{
    __shared__ float red1[4];
    __shared__ float red2[4];
    const int i = blockIdx.x;
    const int t = threadIdx.x;
    const int h = (HEADS == 4) ? (t >> 6) : 0;
    const float denom = s[i*HEADS + h] + 1e-16f;
    const float val = msgacc[(size_t)i*256 + t] / denom + b2f(skip[(size_t)i*256 + t]);

    const int wid = t >> 6, lane = t & 63;
    float sum = val;
    #pragma unroll
    for (int off = 1; off < 64; off <<= 1) sum += __shfl_xor(sum, off, 64);
    if (lane == 0) red1[wid] = sum;
    __syncthreads();
    const float mu = (red1[0] + red1[1] + red1[2] + red1[3]) * (1.f/256.f);
    const float d = val - mu;
    float vs = d * d;
    #pragma unroll
    for (int off = 1; off < 64; off <<= 1) vs += __shfl_xor(vs, off, 64);
    if (lane == 0) red2[wid] = vs;
    __syncthreads();
    const float var = (red2[0] + red2[1] + red2[2] + red2[3]) * (1.f/256.f);
    float y = d * rsqrtf(var + 1e-5f) * gf[t] + bf_[t];
    if (RELU) y = fmaxf(y, 0.f);
    const bool of32 = outmode && (flags[1] != 0);
    if (of32) ((float*)out)[(size_t)i*256 + t] = y;
    else      ((bf16*)out)[(size_t)i*256 + t] = f2b(y);
}

extern "C" void kernel_launch(void* const* d_in, const int* in_sizes, int n_in,
                              void* d_out, int out_size, void* d_ws, size_t ws_size,
                              hipStream_t stream) {
    const int* ei = (const int*)d_in[1];

    // ---- workspace layout (bytes), peak ~154.41 MB ----
    char* w = (char*)d_ws;
    bf16*  P      = (bf16*)(w + 0);             // [N,768] qkv, both layers (76.8MB)
    bf16*  xb     = (bf16*)(w + 76800000);      // [N,128] (dead after GEMM0)
    bf16*  skipL1 = (bf16*)(w + 76800000);      // [N,256] (born at GEMM1)
    float* msgacc = (float*)(w + 102400000);    // [N,256] f32 (51.2MB)
    bf16*  Wt     = (bf16*)(w + 102400000);     // overlay: dead before msg memset
    float* biasf  = (float*)(w + 102924288);    // overlay: 1024 f32
    float* s      = (float*)(w + 153600000);    // [N,4] f32
    float* vecs   = (float*)(w + 154400000);    // 6 x 256 f32
    int*   flags  = (int*)  (w + 154406144);
    float* ewf0 = vecs + 0,   *ewf1 = vecs + 256;
    float* gf0  = vecs + 512, *bf0  = vecs + 768;
    float* gf1  = vecs + 1024,*bf1  = vecs + 1280;
    bf16*  skipL0 = (bf16*)d_out;               // d_out as scratch: skip then h, in-place
    bf16*  hbuf   = (bf16*)d_out;

    const int EB = (N_EDGES + 3) / 4;

    detect_kernel<<<1, 64, 0, stream>>>(ei, (const unsigned int*)d_in[0], flags);
    conv_x<<<3125, 256, 0, stream>>>(d_in[0], xb, flags);
    conv_vec6<<<1, 256, 0, stream>>>(d_in[9], d_in[20], d_in[12], d_in[13],
                                     d_in[23], d_in[24], vecs, flags);

    // ---------------- layer 0 ----------------
    trans_w<128><<<dim3(16,4), 256, 0, stream>>>(
        d_in[3], d_in[5], d_in[7], d_in[10],       // q_w0,k_w0,v_w0,skip_w0
        d_in[4], d_in[6], d_in[8], d_in[11],       // biases
        Wt, biasf, flags);
    gemm_qkvs<128><<<dim3(782,16), 256, 0, stream>>>(xb, Wt, biasf, P, skipL0);
    hipMemsetAsync(msgacc, 0, (size_t)N_NODES*256*4, stream);
    hipMemsetAsync(s,      0, (size_t)N_NODES*4*4, stream);
    edge_pass<4><<<EB, 256, 0, stream>>>(P, ei, d_in[2], ewf0, flags, s, msgacc);
    node_epilogue<4, true><<<N_NODES, 256, 0, stream>>>(
        msgacc, s, skipL0, gf0, bf0, hbuf, flags, 0);

    // ---------------- layer 1 ----------------
    trans_w<256><<<dim3(16,4), 256, 0, stream>>>(
        d_in[14], d_in[16], d_in[18], d_in[21],
        d_in[15], d_in[17], d_in[19], d_in[22],
        Wt, biasf, flags);
    gemm_qkvs<256><<<dim3(782,16), 256, 0, stream>>>(hbuf, Wt, biasf, P, skipL1);
    hipMemsetAsync(msgacc, 0, (size_t)N_NODES*256*4, stream);
    hipMemsetAsync(s,      0, (size_t)N_NODES*4, stream);
    edge_pass<1><<<EB, 256, 0, stream>>>(P, ei, d_in[2], ewf1, flags, s, msgacc);
    node_epilogue<1, false><<<N_NODES, 256, 0, stream>>>(
        msgacc, s, skipL1, gf1, bf1, d_out, flags, 1);
}

// Round 5
// 776.973 us; speedup vs baseline: 5.4199x; 2.4512x over previous
//
#include <hip/hip_runtime.h>
#include <hip/hip_bf16.h>
#include <math.h>

#define N_NODES 50000
#define N_EDGES 800000

typedef __hip_bfloat16 bf16;
typedef __attribute__((ext_vector_type(8))) short frag_ab;   // 8 bf16
typedef __attribute__((ext_vector_type(4))) float frag_cd;   // 4 f32

__device__ __forceinline__ float b2f(bf16 v){ return __bfloat162float(v); }
__device__ __forceinline__ bf16 f2b(float v){ return __float2bfloat16(v); }
__device__ __forceinline__ float bfbits(unsigned int h){
    union { float f; unsigned int u; } w; w.u = h << 16; return w.f;
}
__device__ __forceinline__ void ld4bf(const bf16* p, float f[4]){
    uint2 u = *(const uint2*)p;
    f[0] = bfbits(u.x & 0xFFFFu); f[1] = bfbits(u.x >> 16);
    f[2] = bfbits(u.y & 0xFFFFu); f[3] = bfbits(u.y >> 16);
}
__device__ __forceinline__ float ldrt(const void* p, size_t i, bool f32){
    return f32 ? ((const float*)p)[i] : b2f(((const bf16*)p)[i]);
}

// flags[0] = edge_index is int64; flags[1] = float tensors are float32
__global__ void detect_kernel(const int* __restrict__ ei,
                              const unsigned int* __restrict__ xw,
                              int* __restrict__ flags){
    if (threadIdx.x == 0 && blockIdx.x == 0){
        int i64 = 1;
        for (int j = 0; j < 256; ++j)
            if (ei[2*j + 1] != 0){ i64 = 0; break; }
        flags[0] = i64;
        int isf32 = 0;
        for (int j = 0; j < 64; ++j){
            unsigned int w = xw[j];
            float lo = __uint_as_float((w & 0xFFFFu) << 16);
            if (!(fabsf(lo) <= 64.f)){ isf32 = 1; break; }
        }
        flags[1] = isf32;
    }
}

// ---- convert x -> bf16 xb [N,128] ------------------------------------------
__global__ __launch_bounds__(256) void conv_x(const void* __restrict__ xin,
                                              bf16* __restrict__ xb,
                                              const int* __restrict__ flags){
    const size_t i = ((size_t)blockIdx.x*256 + threadIdx.x) * 8;
    if (i >= (size_t)N_NODES*128) return;
    if (flags[1]){
        const float* xf = (const float*)xin;
        #pragma unroll
        for (int j = 0; j < 8; ++j) xb[i+j] = f2b(xf[i+j]);
    } else {
        *(uint4*)(xb + i) = *(const uint4*)((const bf16*)xin + i);
    }
}

// ---- convert 6 small vectors (256 each) -> f32 -----------------------------
__global__ void conv_vec6(const void* p0, const void* p1, const void* p2,
                          const void* p3, const void* p4, const void* p5,
                          float* __restrict__ outv, const int* __restrict__ flags){
    const int t = threadIdx.x;
    const bool f32 = flags[1] != 0;
    outv[0*256+t] = ldrt(p0, t, f32);
    outv[1*256+t] = ldrt(p1, t, f32);
    outv[2*256+t] = ldrt(p2, t, f32);
    outv[3*256+t] = ldrt(p3, t, f32);
    outv[4*256+t] = ldrt(p4, t, f32);
    outv[5*256+t] = ldrt(p5, t, f32);
}

// ---- CSR build: histogram -> scan -> scatter -------------------------------
__global__ __launch_bounds__(256) void hist_kernel(const int* __restrict__ ei,
                                                   int* __restrict__ counts,
                                                   const int* __restrict__ flags){
    const int e = blockIdx.x*256 + threadIdx.x;
    if (e >= N_EDGES) return;
    const bool i64 = flags[0] != 0;
    const int src = i64 ? ei[2*e]             : ei[e];
    const int dst = i64 ? ei[2*(N_EDGES + e)] : ei[N_EDGES + e];
    if ((unsigned)src >= N_NODES || (unsigned)dst >= N_NODES) return;
    atomicAdd(&counts[dst], 1);
}

// 256 threads, each owns 196 consecutive nodes (256*196 = 50176 >= 50000)
__global__ __launch_bounds__(256) void scan_kernel(const int* __restrict__ counts,
                                                   int* __restrict__ offsets,
                                                   int* __restrict__ cursor){
    __shared__ int wsums[4];
    const int t = threadIdx.x;
    const int base = t * 196;
    int sum = 0;
    for (int j = 0; j < 196; ++j){
        const int idx = base + j;
        if (idx < N_NODES) sum += counts[idx];
    }
    const int lane = t & 63, wid = t >> 6;
    int v = sum;
    #pragma unroll
    for (int off = 1; off < 64; off <<= 1){
        const int u = __shfl_up(v, off, 64);
        if (lane >= off) v += u;
    }
    if (lane == 63) wsums[wid] = v;
    __syncthreads();
    int wbase = 0;
    for (int j = 0; j < wid; ++j) wbase += wsums[j];
    int run = wbase + v - sum;          // exclusive prefix for this thread
    for (int j = 0; j < 196; ++j){
        const int idx = base + j;
        if (idx < N_NODES){
            offsets[idx] = run; cursor[idx] = run;
            run += counts[idx];
        }
    }
    if (t == 255) offsets[N_NODES] = run;
}

__global__ __launch_bounds__(256) void scatter_kernel(
    const int* __restrict__ ei, const void* __restrict__ ea,
    int* __restrict__ cursor, int2* __restrict__ edges,
    const int* __restrict__ flags){
    const int e = blockIdx.x*256 + threadIdx.x;
    if (e >= N_EDGES) return;
    const bool i64 = flags[0] != 0, f32 = flags[1] != 0;
    const int src = i64 ? ei[2*e]             : ei[e];
    const int dst = i64 ? ei[2*(N_EDGES + e)] : ei[N_EDGES + e];
    if ((unsigned)src >= N_NODES || (unsigned)dst >= N_NODES) return;
    const float eav = f32 ? ((const float*)ea)[e] : b2f(((const bf16*)ea)[e]);
    const int pos = atomicAdd(&cursor[dst], 1);
    edges[pos] = make_int2(src, __float_as_int(eav));
}

// ---- transpose 4 weight mats [K,256] -> Wt[1024][K] bf16, biases -> f32 ----
template<int K>
__global__ __launch_bounds__(256) void trans_w(
    const void* w0, const void* w1, const void* w2, const void* w3,
    const void* b0, const void* b1, const void* b2, const void* b3,
    bf16* __restrict__ Wt, float* __restrict__ biasf,
    const int* __restrict__ flags)
{
    const bool f32 = flags[1] != 0;
    const int mi = blockIdx.y;
    const void* W = mi==0?w0 : mi==1?w1 : mi==2?w2 : w3;
    const void* B = mi==0?b0 : mi==1?b1 : mi==2?b2 : b3;
    const int t = threadIdx.x;
    if (blockIdx.x == 0) biasf[mi*256 + t] = ldrt(B, t, f32);
    if (t >= K) return;
    const int c0 = blockIdx.x * 16;
    for (int c = c0; c < c0 + 16; ++c)
        Wt[(size_t)(mi*256 + c)*K + t] = f2b(ldrt(W, (size_t)t*256 + c, f32));
}

// ---- MFMA GEMM: P[:, 0:768] = X@W(qkv)+b (stride 768), cols 768.. -> skipb --
#define AST 40
template<int K>
__global__ __launch_bounds__(256) void gemm_qkvs(
    const bf16* __restrict__ X, const bf16* __restrict__ Wt,
    const float* __restrict__ bias,
    bf16* __restrict__ P, bf16* __restrict__ skipb)
{
    __shared__ short As[64*AST];
    __shared__ short Bs[64*AST];
    const int t = threadIdx.x;
    const int wid = t >> 6, lane = t & 63;
    const int quad = lane >> 4, l16 = lane & 15;
    const int m0 = blockIdx.x * 64;
    const int n0 = blockIdx.y * 64;
    const int srow = t >> 2;
    const int scg  = (t & 3) * 8;
    const int arow = m0 + srow;

    frag_cd acc[4] = {};
    for (int k0 = 0; k0 < K; k0 += 32){
        uint4 av = {0,0,0,0};
        if (arow < N_NODES)
            av = *(const uint4*)(X + (size_t)arow*K + k0 + scg);
        *(uint4*)(&As[srow*AST + scg]) = av;
        uint4 bv = *(const uint4*)(Wt + (size_t)(n0 + srow)*K + k0 + scg);
        *(uint4*)(&Bs[srow*AST + scg]) = bv;
        __syncthreads();
        frag_ab af = *(const frag_ab*)(&As[(wid*16 + l16)*AST + quad*8]);
        #pragma unroll
        for (int nt = 0; nt < 4; ++nt){
            frag_ab bfr = *(const frag_ab*)(&Bs[(nt*16 + l16)*AST + quad*8]);
            acc[nt] = __builtin_amdgcn_mfma_f32_16x16x32_bf16(af, bfr, acc[nt], 0, 0, 0);
        }
        __syncthreads();
    }
    #pragma unroll
    for (int nt = 0; nt < 4; ++nt){
        const int gc = n0 + nt*16 + l16;
        const float bsum = bias[gc];
        #pragma unroll
        for (int r = 0; r < 4; ++r){
            const int node = m0 + wid*16 + quad*4 + r;
            if (node < N_NODES){
                const float y = acc[nt][r] + bsum;
                if (gc < 768) P[(size_t)node*768 + gc] = f2b(y);
                else          skipb[(size_t)node*256 + (gc - 768)] = f2b(y);
            }
        }
    }
}

// ---- fused per-node attention + softmax + skip + LN (+ReLU) ----------------
// One wave per dst node. Lane holds channels c = lane*4 .. lane*4+3.
// HEADS==4: head = lane>>4, shfl-reduce over 16 lanes; HEADS==1: over 64.
template<int HEADS, bool RELU, bool OUTDYN>
__global__ __launch_bounds__(256) void node_attn(
    const bf16* __restrict__ P,          // [N,768] q|k|v
    const int2* __restrict__ edges,      // dst-sorted (src, eav)
    const int* __restrict__ offsets,     // [N+1]
    const bf16* __restrict__ skip,       // [N,256]
    const float* __restrict__ ewf,
    const float* __restrict__ gf, const float* __restrict__ bf_,
    void* __restrict__ out, const int* __restrict__ flags)
{
    const int node = blockIdx.x*4 + (threadIdx.x >> 6);
    if (node >= N_NODES) return;
    const int lane = threadIdx.x & 63;
    const int c0 = lane * 4;

    float q4[4], ew4[4];
    ld4bf(P + (size_t)node*768 + c0, q4);
    ew4[0] = ewf[c0]; ew4[1] = ewf[c0+1]; ew4[2] = ewf[c0+2]; ew4[3] = ewf[c0+3];

    const int beg = offsets[node], end = offsets[node+1];
    float s = 0.f;
    float macc[4] = {0.f, 0.f, 0.f, 0.f};
    const float scale = (HEADS == 4) ? 0.125f : 0.0625f;

    int2 rec = (beg < end) ? edges[beg] : make_int2(0, 0);
    for (int e = beg; e < end; ++e){
        const int2 cur = rec;
        if (e + 1 < end) rec = edges[e+1];           // prefetch next record
        const int src = cur.x;
        const float eav = __int_as_float(cur.y);
        const bf16* kv = P + (size_t)src*768 + 256;
        float kf[4], vf[4];
        ld4bf(kv + c0, kf);
        ld4bf(kv + 256 + c0, vf);
        const float ev0 = eav*ew4[0], ev1 = eav*ew4[1];
        const float ev2 = eav*ew4[2], ev3 = eav*ew4[3];
        float p = q4[0]*(kf[0]+ev0) + q4[1]*(kf[1]+ev1)
                + q4[2]*(kf[2]+ev2) + q4[3]*(kf[3]+ev3);
        if (HEADS == 4){
            #pragma unroll
            for (int off = 1; off < 16; off <<= 1) p += __shfl_xor(p, off, 64);
        } else {
            #pragma unroll
            for (int off = 1; off < 64; off <<= 1) p += __shfl_xor(p, off, 64);
        }
        const float a = expf(fminf(p * scale, 80.f));
        s += a;
        macc[0] += a*(vf[0]+ev0); macc[1] += a*(vf[1]+ev1);
        macc[2] += a*(vf[2]+ev2); macc[3] += a*(vf[3]+ev3);
    }

    // softmax normalize + skip
    const float denom = s + 1e-16f;
    float sk[4];
    ld4bf(skip + (size_t)node*256 + c0, sk);
    float val[4];
    #pragma unroll
    for (int j = 0; j < 4; ++j) val[j] = macc[j]/denom + sk[j];

    // LayerNorm over 256 channels (whole wave)
    float sum = val[0]+val[1]+val[2]+val[3];
    #pragma unroll
    for (int off = 1; off < 64; off <<= 1) sum += __shfl_xor(sum, off, 64);
    const float mu = sum * (1.f/256.f);
    float vs = 0.f;
    #pragma unroll
    for (int j = 0; j < 4; ++j){ const float d = val[j]-mu; vs += d*d; }
    #pragma unroll
    for (int off = 1; off < 64; off <<= 1) vs += __shfl_xor(vs, off, 64);
    const float rstd = rsqrtf(vs * (1.f/256.f) + 1e-5f);

    float y[4];
    #pragma unroll
    for (int j = 0; j < 4; ++j){
        y[j] = (val[j]-mu) * rstd * gf[c0+j] + bf_[c0+j];
        if (RELU) y[j] = fmaxf(y[j], 0.f);
    }
    const bool of32 = OUTDYN && (flags[1] != 0);
    if (of32){
        float4 o = {y[0], y[1], y[2], y[3]};
        *(float4*)((float*)out + (size_t)node*256 + c0) = o;
    } else {
        uint2 o;
        o.x = ((unsigned)__bfloat16_as_ushort(f2b(y[0]))) |
              (((unsigned)__bfloat16_as_ushort(f2b(y[1]))) << 16);
        o.y = ((unsigned)__bfloat16_as_ushort(f2b(y[2]))) |
              (((unsigned)__bfloat16_as_ushort(f2b(y[3]))) << 16);
        *(uint2*)((bf16*)out + (size_t)node*256 + c0) = o;
    }
}

extern "C" void kernel_launch(void* const* d_in, const int* in_sizes, int n_in,
                              void* d_out, int out_size, void* d_ws, size_t ws_size,
                              hipStream_t stream) {
    const int* ei = (const int*)d_in[1];

    // ---- workspace layout (bytes), peak ~110 MB ----
    char* w = (char*)d_ws;
    bf16*  P       = (bf16*) (w + 0);            // [N,768] (76.8MB)
    bf16*  xb      = (bf16*) (w + 76800000);     // [N,128] (dead after GEMM0)
    bf16*  skipL1  = (bf16*) (w + 76800000);     // [N,256] (born at GEMM1)
    bf16*  Wt      = (bf16*) (w + 102400000);    // 1024*256*2 = 524288
    float* biasf   = (float*)(w + 102924288);    // 4KB
    int*   counts  = (int*)  (w + 102928384);    // 200KB
    int*   offsets = (int*)  (w + 103128384);    // 200KB+4
    int*   cursor  = (int*)  (w + 103328388);    // 200KB
    int2*  edges   = (int2*) (w + 103528392);    // 6.4MB
    float* vecs    = (float*)(w + 109928400);    // 6x256 f32
    int*   flags   = (int*)  (w + 109934544);
    float* ewf0 = vecs + 0,   *ewf1 = vecs + 256;
    float* gf0  = vecs + 512, *bf0  = vecs + 768;
    float* gf1  = vecs + 1024,*bf1  = vecs + 1280;
    bf16*  skipL0 = (bf16*)d_out;   // d_out as scratch: skip -> h in-place
    bf16*  hbuf   = (bf16*)d_out;

    const int EB = (N_EDGES + 255) / 256;
    const int NB = (N_NODES + 3) / 4;

    detect_kernel<<<1, 64, 0, stream>>>(ei, (const unsigned int*)d_in[0], flags);
    hipMemsetAsync(counts, 0, (size_t)N_NODES*4, stream);
    conv_x<<<3125, 256, 0, stream>>>(d_in[0], xb, flags);
    conv_vec6<<<1, 256, 0, stream>>>(d_in[9], d_in[20], d_in[12], d_in[13],
                                     d_in[23], d_in[24], vecs, flags);
    // CSR build (once, shared by both layers)
    hist_kernel<<<EB, 256, 0, stream>>>(ei, counts, flags);
    scan_kernel<<<1, 256, 0, stream>>>(counts, offsets, cursor);
    scatter_kernel<<<EB, 256, 0, stream>>>(ei, d_in[2], cursor, edges, flags);

    // ---------------- layer 0 ----------------
    trans_w<128><<<dim3(16,4), 256, 0, stream>>>(
        d_in[3], d_in[5], d_in[7], d_in[10],
        d_in[4], d_in[6], d_in[8], d_in[11],
        Wt, biasf, flags);
    gemm_qkvs<128><<<dim3(782,16), 256, 0, stream>>>(xb, Wt, biasf, P, skipL0);
    node_attn<4, true, false><<<NB, 256, 0, stream>>>(
        P, edges, offsets, skipL0, ewf0, gf0, bf0, hbuf, flags);

    // ---------------- layer 1 ----------------
    trans_w<256><<<dim3(16,4), 256, 0, stream>>>(
        d_in[14], d_in[16], d_in[18], d_in[21],
        d_in[15], d_in[17], d_in[19], d_in[22],
        Wt, biasf, flags);
    gemm_qkvs<256><<<dim3(782,16), 256, 0, stream>>>(hbuf, Wt, biasf, P, skipL1);
    node_attn<1, false, true><<<NB, 256, 0, stream>>>(
        P, edges, offsets, skipL1, ewf1, gf1, bf1, d_out, flags);
}

// Round 6
// 653.679 us; speedup vs baseline: 6.4422x; 1.1886x over previous
//
#include <hip/hip_runtime.h>
#include <hip/hip_bf16.h>
#include <math.h>

#define N_NODES 50000
#define N_EDGES 800000
#define SCAN_B 196            // 196 blocks x 256 = 50176 >= N_NODES

typedef __hip_bfloat16 bf16;
typedef __attribute__((ext_vector_type(8))) short frag_ab;   // 8 bf16
typedef __attribute__((ext_vector_type(4))) float frag_cd;   // 4 f32

__device__ __forceinline__ float b2f(bf16 v){ return __bfloat162float(v); }
__device__ __forceinline__ bf16 f2b(float v){ return __float2bfloat16(v); }
__device__ __forceinline__ float bfbits(unsigned int h){
    union { float f; unsigned int u; } w; w.u = h << 16; return w.f;
}
__device__ __forceinline__ void ld4bf(const bf16* p, float f[4]){
    uint2 u = *(const uint2*)p;
    f[0] = bfbits(u.x & 0xFFFFu); f[1] = bfbits(u.x >> 16);
    f[2] = bfbits(u.y & 0xFFFFu); f[3] = bfbits(u.y >> 16);
}
__device__ __forceinline__ float ldrt(const void* p, size_t i, bool f32){
    return f32 ? ((const float*)p)[i] : b2f(((const bf16*)p)[i]);
}

// flags[0] = edge_index is int64; flags[1] = float tensors are float32
__global__ void detect_kernel(const int* __restrict__ ei,
                              const unsigned int* __restrict__ xw,
                              int* __restrict__ flags){
    if (threadIdx.x == 0 && blockIdx.x == 0){
        int i64 = 1;
        for (int j = 0; j < 256; ++j)
            if (ei[2*j + 1] != 0){ i64 = 0; break; }
        flags[0] = i64;
        int isf32 = 0;
        for (int j = 0; j < 64; ++j){
            unsigned int w = xw[j];
            float lo = __uint_as_float((w & 0xFFFFu) << 16);
            if (!(fabsf(lo) <= 64.f)){ isf32 = 1; break; }
        }
        flags[1] = isf32;
    }
}

// ---- convert x -> bf16 xb [N,128] ------------------------------------------
__global__ __launch_bounds__(256) void conv_x(const void* __restrict__ xin,
                                              bf16* __restrict__ xb,
                                              const int* __restrict__ flags){
    const size_t i = ((size_t)blockIdx.x*256 + threadIdx.x) * 8;
    if (i >= (size_t)N_NODES*128) return;
    if (flags[1]){
        const float* xf = (const float*)xin;
        #pragma unroll
        for (int j = 0; j < 8; ++j) xb[i+j] = f2b(xf[i+j]);
    } else {
        *(uint4*)(xb + i) = *(const uint4*)((const bf16*)xin + i);
    }
}

// ---- convert 6 small vectors (256 each) -> f32 -----------------------------
__global__ void conv_vec6(const void* p0, const void* p1, const void* p2,
                          const void* p3, const void* p4, const void* p5,
                          float* __restrict__ outv, const int* __restrict__ flags){
    const int t = threadIdx.x;
    const bool f32 = flags[1] != 0;
    outv[0*256+t] = ldrt(p0, t, f32);
    outv[1*256+t] = ldrt(p1, t, f32);
    outv[2*256+t] = ldrt(p2, t, f32);
    outv[3*256+t] = ldrt(p3, t, f32);
    outv[4*256+t] = ldrt(p4, t, f32);
    outv[5*256+t] = ldrt(p5, t, f32);
}

// ---- CSR build: histogram -> 3-phase parallel scan -> scatter --------------
__global__ __launch_bounds__(256) void hist_kernel(const int* __restrict__ ei,
                                                   int* __restrict__ counts,
                                                   const int* __restrict__ flags){
    const int e = blockIdx.x*256 + threadIdx.x;
    if (e >= N_EDGES) return;
    const bool i64 = flags[0] != 0;
    const int src = i64 ? ei[2*e]             : ei[e];
    const int dst = i64 ? ei[2*(N_EDGES + e)] : ei[N_EDGES + e];
    if ((unsigned)src >= N_NODES || (unsigned)dst >= N_NODES) return;
    atomicAdd(&counts[dst], 1);
}

__global__ __launch_bounds__(256) void scan_phase1(const int* __restrict__ counts,
                                                   int* __restrict__ bsum){
    __shared__ int ws[4];
    const int idx = blockIdx.x*256 + threadIdx.x;
    int v = (idx < N_NODES) ? counts[idx] : 0;
    const int lane = threadIdx.x & 63, wid = threadIdx.x >> 6;
    #pragma unroll
    for (int off = 1; off < 64; off <<= 1) v += __shfl_xor(v, off, 64);
    if (lane == 0) ws[wid] = v;
    __syncthreads();
    if (threadIdx.x == 0) bsum[blockIdx.x] = ws[0]+ws[1]+ws[2]+ws[3];
}

// single block: exclusive scan of bsum[SCAN_B] -> bbase[SCAN_B]
__global__ __launch_bounds__(256) void scan_phase2(const int* __restrict__ bsum,
                                                   int* __restrict__ bbase){
    __shared__ int ws[4];
    const int t = threadIdx.x;
    const int lane = t & 63, wid = t >> 6;
    int v = (t < SCAN_B) ? bsum[t] : 0;
    int incl = v;
    #pragma unroll
    for (int off = 1; off < 64; off <<= 1){
        const int u = __shfl_up(incl, off, 64);
        if (lane >= off) incl += u;
    }
    if (lane == 63) ws[wid] = incl;
    __syncthreads();
    int wb = 0;
    for (int j = 0; j < wid; ++j) wb += ws[j];
    if (t < SCAN_B) bbase[t] = wb + incl - v;   // exclusive
}

__global__ __launch_bounds__(256) void scan_phase3(const int* __restrict__ counts,
                                                   const int* __restrict__ bbase,
                                                   int* __restrict__ offsets,
                                                   int* __restrict__ cursor){
    __shared__ int ws[4];
    const int idx = blockIdx.x*256 + threadIdx.x;
    const int lane = threadIdx.x & 63, wid = threadIdx.x >> 6;
    const int v = (idx < N_NODES) ? counts[idx] : 0;
    int incl = v;
    #pragma unroll
    for (int off = 1; off < 64; off <<= 1){
        const int u = __shfl_up(incl, off, 64);
        if (lane >= off) incl += u;
    }
    if (lane == 63) ws[wid] = incl;
    __syncthreads();
    int wb = bbase[blockIdx.x];
    for (int j = 0; j < wid; ++j) wb += ws[j];
    const int excl = wb + incl - v;
    if (idx < N_NODES){
        offsets[idx] = excl; cursor[idx] = excl;
        if (idx == N_NODES-1) offsets[N_NODES] = excl + v;
    }
}

__global__ __launch_bounds__(256) void scatter_kernel(
    const int* __restrict__ ei, const void* __restrict__ ea,
    int* __restrict__ cursor, int2* __restrict__ edges,
    const int* __restrict__ flags){
    const int e = blockIdx.x*256 + threadIdx.x;
    if (e >= N_EDGES) return;
    const bool i64 = flags[0] != 0, f32 = flags[1] != 0;
    const int src = i64 ? ei[2*e]             : ei[e];
    const int dst = i64 ? ei[2*(N_EDGES + e)] : ei[N_EDGES + e];
    if ((unsigned)src >= N_NODES || (unsigned)dst >= N_NODES) return;
    const float eav = f32 ? ((const float*)ea)[e] : b2f(((const bf16*)ea)[e]);
    const int pos = atomicAdd(&cursor[dst], 1);
    edges[pos] = make_int2(src, __float_as_int(eav));
}

// ---- transpose 4 weight mats [K,256] -> Wt[1024][K] bf16, biases -> f32 ----
template<int K>
__global__ __launch_bounds__(256) void trans_w(
    const void* w0, const void* w1, const void* w2, const void* w3,
    const void* b0, const void* b1, const void* b2, const void* b3,
    bf16* __restrict__ Wt, float* __restrict__ biasf,
    const int* __restrict__ flags)
{
    const bool f32 = flags[1] != 0;
    const int mi = blockIdx.y;
    const void* W = mi==0?w0 : mi==1?w1 : mi==2?w2 : w3;
    const void* B = mi==0?b0 : mi==1?b1 : mi==2?b2 : b3;
    const int t = threadIdx.x;
    if (blockIdx.x == 0) biasf[mi*256 + t] = ldrt(B, t, f32);
    if (t >= K) return;
    const int c0 = blockIdx.x * 16;
    for (int c = c0; c < c0 + 16; ++c)
        Wt[(size_t)(mi*256 + c)*K + t] = f2b(ldrt(W, (size_t)t*256 + c, f32));
}

// ---- MFMA GEMM: P[:, 0:768] = X@W(qkv)+b (stride 768), cols 768.. -> skipb --
#define AST 40
template<int K>
__global__ __launch_bounds__(256) void gemm_qkvs(
    const bf16* __restrict__ X, const bf16* __restrict__ Wt,
    const float* __restrict__ bias,
    bf16* __restrict__ P, bf16* __restrict__ skipb)
{
    __shared__ short As[64*AST];
    __shared__ short Bs[64*AST];
    const int t = threadIdx.x;
    const int wid = t >> 6, lane = t & 63;
    const int quad = lane >> 4, l16 = lane & 15;
    const int m0 = blockIdx.x * 64;
    const int n0 = blockIdx.y * 64;
    const int srow = t >> 2;
    const int scg  = (t & 3) * 8;
    const int arow = m0 + srow;

    frag_cd acc[4] = {};
    for (int k0 = 0; k0 < K; k0 += 32){
        uint4 av = {0,0,0,0};
        if (arow < N_NODES)
            av = *(const uint4*)(X + (size_t)arow*K + k0 + scg);
        *(uint4*)(&As[srow*AST + scg]) = av;
        uint4 bv = *(const uint4*)(Wt + (size_t)(n0 + srow)*K + k0 + scg);
        *(uint4*)(&Bs[srow*AST + scg]) = bv;
        __syncthreads();
        frag_ab af = *(const frag_ab*)(&As[(wid*16 + l16)*AST + quad*8]);
        #pragma unroll
        for (int nt = 0; nt < 4; ++nt){
            frag_ab bfr = *(const frag_ab*)(&Bs[(nt*16 + l16)*AST + quad*8]);
            acc[nt] = __builtin_amdgcn_mfma_f32_16x16x32_bf16(af, bfr, acc[nt], 0, 0, 0);
        }
        __syncthreads();
    }
    #pragma unroll
    for (int nt = 0; nt < 4; ++nt){
        const int gc = n0 + nt*16 + l16;
        const float bsum = bias[gc];
        #pragma unroll
        for (int r = 0; r < 4; ++r){
            const int node = m0 + wid*16 + quad*4 + r;
            if (node < N_NODES){
                const float y = acc[nt][r] + bsum;
                if (gc < 768) P[(size_t)node*768 + gc] = f2b(y);
                else          skipb[(size_t)node*256 + (gc - 768)] = f2b(y);
            }
        }
    }
}

// ---- fused per-node attention + softmax + skip + LN (+ReLU) ----------------
template<int HEADS, bool RELU, bool OUTDYN>
__global__ __launch_bounds__(256) void node_attn(
    const bf16* __restrict__ P,          // [N,768] q|k|v
    const int2* __restrict__ edges,      // dst-sorted (src, eav)
    const int* __restrict__ offsets,     // [N+1]
    const bf16* __restrict__ skip,       // [N,256]
    const float* __restrict__ ewf,
    const float* __restrict__ gf, const float* __restrict__ bf_,
    void* __restrict__ out, const int* __restrict__ flags)
{
    const int node = blockIdx.x*4 + (threadIdx.x >> 6);
    if (node >= N_NODES) return;
    const int lane = threadIdx.x & 63;
    const int c0 = lane * 4;

    float q4[4], ew4[4];
    ld4bf(P + (size_t)node*768 + c0, q4);
    ew4[0] = ewf[c0]; ew4[1] = ewf[c0+1]; ew4[2] = ewf[c0+2]; ew4[3] = ewf[c0+3];

    const int beg = offsets[node], end = offsets[node+1];
    float s = 0.f;
    float macc[4] = {0.f, 0.f, 0.f, 0.f};
    const float scale = (HEADS == 4) ? 0.125f : 0.0625f;

    int2 rec = (beg < end) ? edges[beg] : make_int2(0, 0);
    for (int e = beg; e < end; ++e){
        const int2 cur = rec;
        if (e + 1 < end) rec = edges[e+1];           // prefetch next record
        const int src = cur.x;
        const float eav = __int_as_float(cur.y);
        const bf16* kv = P + (size_t)src*768 + 256;
        float kf[4], vf[4];
        ld4bf(kv + c0, kf);
        ld4bf(kv + 256 + c0, vf);
        const float ev0 = eav*ew4[0], ev1 = eav*ew4[1];
        const float ev2 = eav*ew4[2], ev3 = eav*ew4[3];
        float p = q4[0]*(kf[0]+ev0) + q4[1]*(kf[1]+ev1)
                + q4[2]*(kf[2]+ev2) + q4[3]*(kf[3]+ev3);
        if (HEADS == 4){
            #pragma unroll
            for (int off = 1; off < 16; off <<= 1) p += __shfl_xor(p, off, 64);
        } else {
            #pragma unroll
            for (int off = 1; off < 64; off <<= 1) p += __shfl_xor(p, off, 64);
        }
        const float a = expf(fminf(p * scale, 80.f));
        s += a;
        macc[0] += a*(vf[0]+ev0); macc[1] += a*(vf[1]+ev1);
        macc[2] += a*(vf[2]+ev2); macc[3] += a*(vf[3]+ev3);
    }

    const float denom = s + 1e-16f;
    float sk[4];
    ld4bf(skip + (size_t)node*256 + c0, sk);
    float val[4];
    #pragma unroll
    for (int j = 0; j < 4; ++j) val[j] = macc[j]/denom + sk[j];

    float sum = val[0]+val[1]+val[2]+val[3];
    #pragma unroll
    for (int off = 1; off < 64; off <<= 1) sum += __shfl_xor(sum, off, 64);
    const float mu = sum * (1.f/256.f);
    float vs = 0.f;
    #pragma unroll
    for (int j = 0; j < 4; ++j){ const float d = val[j]-mu; vs += d*d; }
    #pragma unroll
    for (int off = 1; off < 64; off <<= 1) vs += __shfl_xor(vs, off, 64);
    const float rstd = rsqrtf(vs * (1.f/256.f) + 1e-5f);

    float y[4];
    #pragma unroll
    for (int j = 0; j < 4; ++j){
        y[j] = (val[j]-mu) * rstd * gf[c0+j] + bf_[c0+j];
        if (RELU) y[j] = fmaxf(y[j], 0.f);
    }
    const bool of32 = OUTDYN && (flags[1] != 0);
    if (of32){
        float4 o = {y[0], y[1], y[2], y[3]};
        *(float4*)((float*)out + (size_t)node*256 + c0) = o;
    } else {
        uint2 o;
        o.x = ((unsigned)__bfloat16_as_ushort(f2b(y[0]))) |
              (((unsigned)__bfloat16_as_ushort(f2b(y[1]))) << 16);
        o.y = ((unsigned)__bfloat16_as_ushort(f2b(y[2]))) |
              (((unsigned)__bfloat16_as_ushort(f2b(y[3]))) << 16);
        *(uint2*)((bf16*)out + (size_t)node*256 + c0) = o;
    }
}

extern "C" void kernel_launch(void* const* d_in, const int* in_sizes, int n_in,
                              void* d_out, int out_size, void* d_ws, size_t ws_size,
                              hipStream_t stream) {
    const int* ei = (const int*)d_in[1];

    // ---- workspace layout (bytes), peak ~110 MB ----
    char* w = (char*)d_ws;
    bf16*  P       = (bf16*) (w + 0);            // [N,768] (76.8MB)
    bf16*  xb      = (bf16*) (w + 76800000);     // [N,128] (dead after GEMM0)
    bf16*  skipL1  = (bf16*) (w + 76800000);     // [N,256] (born at GEMM1)
    bf16*  Wt      = (bf16*) (w + 102400000);    // 1024*256*2 = 524288
    float* biasf   = (float*)(w + 102924288);    // 4KB
    int*   counts  = (int*)  (w + 102928384);    // 200KB
    int*   offsets = (int*)  (w + 103128384);    // 200KB+4
    int*   cursor  = (int*)  (w + 103328388);    // 200KB
    int2*  edges   = (int2*) (w + 103528392);    // 6.4MB
    float* vecs    = (float*)(w + 109928400);    // 6x256 f32
    int*   flags   = (int*)  (w + 109934544);
    int*   bsum    = (int*)  (w + 109934608);    // SCAN_B ints
    int*   bbase   = (int*)  (w + 109935392);    // SCAN_B ints
    float* ewf0 = vecs + 0,   *ewf1 = vecs + 256;
    float* gf0  = vecs + 512, *bf0  = vecs + 768;
    float* gf1  = vecs + 1024,*bf1  = vecs + 1280;
    bf16*  skipL0 = (bf16*)d_out;   // d_out as scratch: skip -> h in-place
    bf16*  hbuf   = (bf16*)d_out;

    const int EB = (N_EDGES + 255) / 256;
    const int NB = (N_NODES + 3) / 4;

    detect_kernel<<<1, 64, 0, stream>>>(ei, (const unsigned int*)d_in[0], flags);
    hipMemsetAsync(counts, 0, (size_t)N_NODES*4, stream);
    conv_x<<<3125, 256, 0, stream>>>(d_in[0], xb, flags);
    conv_vec6<<<1, 256, 0, stream>>>(d_in[9], d_in[20], d_in[12], d_in[13],
                                     d_in[23], d_in[24], vecs, flags);
    // CSR build (once, shared by both layers)
    hist_kernel<<<EB, 256, 0, stream>>>(ei, counts, flags);
    scan_phase1<<<SCAN_B, 256, 0, stream>>>(counts, bsum);
    scan_phase2<<<1, 256, 0, stream>>>(bsum, bbase);
    scan_phase3<<<SCAN_B, 256, 0, stream>>>(counts, bbase, offsets, cursor);
    scatter_kernel<<<EB, 256, 0, stream>>>(ei, d_in[2], cursor, edges, flags);

    // ---------------- layer 0 ----------------
    trans_w<128><<<dim3(16,4), 256, 0, stream>>>(
        d_in[3], d_in[5], d_in[7], d_in[10],
        d_in[4], d_in[6], d_in[8], d_in[11],
        Wt, biasf, flags);
    gemm_qkvs<128><<<dim3(782,16), 256, 0, stream>>>(xb, Wt, biasf, P, skipL0);
    node_attn<4, true, false><<<NB, 256, 0, stream>>>(
        P, edges, offsets, skipL0, ewf0, gf0, bf0, hbuf, flags);

    // ---------------- layer 1 ----------------
    trans_w<256><<<dim3(16,4), 256, 0, stream>>>(
        d_in[14], d_in[16], d_in[18], d_in[21],
        d_in[15], d_in[17], d_in[19], d_in[22],
        Wt, biasf, flags);
    gemm_qkvs<256><<<dim3(782,16), 256, 0, stream>>>(hbuf, Wt, biasf, P, skipL1);
    node_attn<1, false, true><<<NB, 256, 0, stream>>>(
        P, edges, offsets, skipL1, ewf1, gf1, bf1, d_out, flags);
}